// Round 8
// baseline (207.556 us; speedup 1.0000x reference)
//
#include <hip/hip_runtime.h>
#include <hip/hip_bf16.h>
#include <cstddef>
#include <cstdint>

#define B_SZ   2
#define T_SEQ  2048
#define E_DIM  1024
#define N_HEAD 16
#define HEAD   64

typedef unsigned short u16;
typedef unsigned int u32;
using frag8 = __attribute__((ext_vector_type(8))) short;   // 8 bf16 = 4 VGPRs
using f32x4 = __attribute__((ext_vector_type(4))) float;   // MFMA accumulator

__device__ inline u16 f2bf(float x) {
    __hip_bfloat16 h = __float2bfloat16(x);
    return *reinterpret_cast<u16*>(&h);
}

// pair-pack two f32 -> one u32 of 2x bf16 (lo=first, hi=second), RNE.
// COMPILER-emitted conversion (hazard-safe) -- round-5 lesson: raw inline-asm
// around transcendental/convert ops corrupted results.
__device__ inline u32 pack_bf16x2(float lo, float hi) {
    float2 t; t.x = lo; t.y = hi;
    __hip_bfloat162 p = __float22bfloat162_rn(t);
    return *reinterpret_cast<u32*>(&p);
}

// async global->LDS, 16 B per lane. LDS dest is wave-uniform base; HW adds lane*16B.
__device__ inline void gl2lds16(const void* g, void* l) {
    auto gp = reinterpret_cast<const __attribute__((address_space(1))) unsigned int*>(
        reinterpret_cast<uintptr_t>(g));
    auto lp = reinterpret_cast<__attribute__((address_space(3))) unsigned int*>(
        reinterpret_cast<uintptr_t>(l));
    __builtin_amdgcn_global_load_lds(gp, lp, 16, 0, 0);
}

// ---------------------------------------------------------------------------
// Cast WEIGHTS ONLY to bf16 (q/k/v conversion is fused into gemm_qkv's
// A-staging -- saves a full 75 MB pass over the activations).
// Wq is pre-scaled by 1/8 (EXACT in bf16) so attention scores need no scaling.
// ---------------------------------------------------------------------------
struct CastArgs {
    const float* src[4];
    u16* dst[4];
    int n[4];
    float scale[4];
};

__global__ __launch_bounds__(256) void cast_f32_bf16(CastArgs a) {
    const int t = blockIdx.y;
    const int i0 = (blockIdx.x * 256 + threadIdx.x) * 8;
    if (i0 >= a.n[t]) return;
    const float sc = a.scale[t];
    const float4 f0 = *(const float4*)(a.src[t] + i0);
    const float4 f1 = *(const float4*)(a.src[t] + i0 + 4);
    uint4 r;
    r.x = pack_bf16x2(f0.x * sc, f0.y * sc);
    r.y = pack_bf16x2(f0.z * sc, f0.w * sc);
    r.z = pack_bf16x2(f1.x * sc, f1.y * sc);
    r.w = pack_bf16x2(f1.z * sc, f1.w * sc);
    *(uint4*)(a.dst[t] + i0) = r;
}

// ---------------------------------------------------------------------------
// bf16 MFMA GEMM core: Y = X @ W^T. BM=64 x BN=128, BK=64 (empirical optimum
// across 4 structure rounds). DOUBLE-BUFFERED staging: B via width-16 glds;
// A either glds (AF32=false, bf16 input) or FUSED f32->bf16 reg-staging
// (AF32=true): 4x float4 loads issued BEFORE the MFMA block, cvt+ds_write_b128
// AFTER it (T14 issue-early/write-late: HBM latency hides under compute).
// Same 8-slot XOR chunk swizzle both paths (0 conflicts measured). 4 waves,
// each 32x64. 48 KB LDS -> 3 blocks/CU.
// mode 0: bf16 scatter [B,H,T,64]; mode 1: fp32 [M,1024]; mode 2: bf16 [B,H,64,T]
// ---------------------------------------------------------------------------
template <bool AF32>
__device__ inline void gemm_core(const void* __restrict__ Xv,
                                 const u16* __restrict__ W,
                                 void* __restrict__ Yv, int mode,
                                 int bm0, int bn0) {
    __shared__ u16 As[2][64 * 64];    // 8 KB x2
    __shared__ u16 Bs[2][128 * 64];   // 16 KB x2

    const int tid = threadIdx.x;
    const int w = tid >> 6;
    const int lane = tid & 63;
    const int ln = lane & 15;
    const int quad = lane >> 4;
    const int wm = (w & 1) * 32;
    const int wn = (w >> 1) * 64;

    const int l8 = lane >> 3;              // sub-row 0..7
    const int g = (lane & 7) ^ l8;         // global chunk fetched (XOR swizzle)

    // A source pointers: same (row, chunk) geometry for both paths
    const u16* Ag = AF32 ? nullptr
        : (const u16*)Xv + (size_t)(bm0 + w * 16 + l8) * 1024 + g * 8;
    const float* Af = AF32
        ? (const float*)Xv + (size_t)(bm0 + w * 16 + l8) * 1024 + g * 8 : nullptr;
    const u16* Bg = W + (size_t)(bn0 + w * 32 + l8) * 1024 + g * 8;
    const int al = __builtin_amdgcn_readfirstlane(w * 1024);
    const int bl = __builtin_amdgcn_readfirstlane(w * 2048);

    const f32x4 zf = {0.f, 0.f, 0.f, 0.f};
    f32x4 acc[2][4];
#pragma unroll
    for (int mi = 0; mi < 2; ++mi)
#pragma unroll
        for (int nj = 0; nj < 4; ++nj) acc[mi][nj] = zf;

    const int sw = ln & 7;

    // preload K-tile 0 into buffer 0
    if constexpr (AF32) {
        const float4 p00 = *(const float4*)Af;
        const float4 p01 = *(const float4*)(Af + 4);
        const float4 p10 = *(const float4*)(Af + 8 * 1024);
        const float4 p11 = *(const float4*)(Af + 8 * 1024 + 4);
        uint4 r0, r1;
        r0.x = pack_bf16x2(p00.x, p00.y); r0.y = pack_bf16x2(p00.z, p00.w);
        r0.z = pack_bf16x2(p01.x, p01.y); r0.w = pack_bf16x2(p01.z, p01.w);
        r1.x = pack_bf16x2(p10.x, p10.y); r1.y = pack_bf16x2(p10.z, p10.w);
        r1.z = pack_bf16x2(p11.x, p11.y); r1.w = pack_bf16x2(p11.z, p11.w);
        *(uint4*)(&As[0][0] + al + lane * 8) = r0;
        *(uint4*)(&As[0][0] + al + 512 + lane * 8) = r1;
    } else {
        gl2lds16(Ag, &As[0][0] + al);
        gl2lds16(Ag + 8 * 1024, &As[0][0] + al + 512);
    }
#pragma unroll
    for (int it = 0; it < 4; ++it)
        gl2lds16(Bg + (size_t)it * 8 * 1024, &Bs[0][0] + bl + it * 512);

    for (int k0 = 0; k0 < 1024; k0 += 64) {
        const int buf = (k0 >> 6) & 1;
        __syncthreads();   // drains this tile's glds + ds_writes; prev reads done

        const bool pre = (k0 + 64 < 1024);
        float4 a00, a01, a10, a11;   // f32-A prefetch (issue-early)
        if (pre) {
#pragma unroll
            for (int it = 0; it < 4; ++it)
                gl2lds16(Bg + (size_t)it * 8 * 1024 + k0 + 64,
                         &Bs[buf ^ 1][0] + bl + it * 512);
            if constexpr (AF32) {
                const float* ap0 = Af + k0 + 64;
                const float* ap1 = Af + 8 * 1024 + k0 + 64;
                a00 = *(const float4*)ap0; a01 = *(const float4*)(ap0 + 4);
                a10 = *(const float4*)ap1; a11 = *(const float4*)(ap1 + 4);
            } else {
                gl2lds16(Ag + k0 + 64, &As[buf ^ 1][0] + al);
                gl2lds16(Ag + 8 * 1024 + k0 + 64, &As[buf ^ 1][0] + al + 512);
            }
        }

        frag8 a[2][2], b[4][2];
#pragma unroll
        for (int kc = 0; kc < 2; ++kc) {
            const int slot = ((kc * 4 + quad) ^ sw) * 8;
#pragma unroll
            for (int mi = 0; mi < 2; ++mi)
                a[mi][kc] = *(const frag8*)(&As[buf][0] + (wm + mi * 16 + ln) * 64 + slot);
#pragma unroll
            for (int nj = 0; nj < 4; ++nj)
                b[nj][kc] = *(const frag8*)(&Bs[buf][0] + (wn + nj * 16 + ln) * 64 + slot);
        }
#pragma unroll
        for (int kc = 0; kc < 2; ++kc)
#pragma unroll
            for (int mi = 0; mi < 2; ++mi)
#pragma unroll
                for (int nj = 0; nj < 4; ++nj)
                    acc[mi][nj] = __builtin_amdgcn_mfma_f32_16x16x32_bf16(
                        a[mi][kc], b[nj][kc], acc[mi][nj], 0, 0, 0);

        // write-late: convert + ds_write the prefetched f32 A into buf^1
        if (AF32 && pre) {
            uint4 r0, r1;
            r0.x = pack_bf16x2(a00.x, a00.y); r0.y = pack_bf16x2(a00.z, a00.w);
            r0.z = pack_bf16x2(a01.x, a01.y); r0.w = pack_bf16x2(a01.z, a01.w);
            r1.x = pack_bf16x2(a10.x, a10.y); r1.y = pack_bf16x2(a10.z, a10.w);
            r1.z = pack_bf16x2(a11.x, a11.y); r1.w = pack_bf16x2(a11.z, a11.w);
            *(uint4*)(&As[buf ^ 1][0] + al + lane * 8) = r0;
            *(uint4*)(&As[buf ^ 1][0] + al + 512 + lane * 8) = r1;
        }
    }

    // C/D layout: col = lane&15, row = quad*4 + reg
#pragma unroll
    for (int mi = 0; mi < 2; ++mi)
#pragma unroll
        for (int nj = 0; nj < 4; ++nj)
#pragma unroll
            for (int reg = 0; reg < 4; ++reg) {
                const int m = bm0 + wm + mi * 16 + quad * 4 + reg;
                const int n = bn0 + wn + nj * 16 + ln;
                if (mode == 1) {
                    ((float*)Yv)[(size_t)m * E_DIM + n] = acc[mi][nj][reg];
                } else {
                    const int b_ = m >> 11, t_ = m & (T_SEQ - 1);
                    const int h_ = n >> 6, d_ = n & (HEAD - 1);
                    const size_t idx = (mode == 0)
                        ? (((size_t)(b_ * N_HEAD + h_)) * T_SEQ + t_) * HEAD + d_
                        : (((size_t)(b_ * N_HEAD + h_)) * HEAD + d_) * T_SEQ + t_;
                    ((u16*)Yv)[idx] = f2bf(acc[mi][nj][reg]);
                }
            }
}

struct QkvArgs {
    const float* X[3];   // ORIGINAL f32 q/k/v (cast fused into A-staging)
    const u16* W[3];
    u16* Y[3];
};

__global__ __launch_bounds__(256, 3) void gemm_qkv(QkvArgs a) {
    const int z = blockIdx.z;
    gemm_core<true>(a.X[z], a.W[z], a.Y[z], z == 2 ? 2 : 0,
                    blockIdx.x * 64, blockIdx.y * 128);
}

__global__ __launch_bounds__(256, 3) void gemm_out(const u16* __restrict__ X,
                                                   const u16* __restrict__ W,
                                                   float* __restrict__ Y) {
    gemm_core<false>(X, W, Y, 1, blockIdx.x * 64, blockIdx.y * 128);
}

// ---------------------------------------------------------------------------
// Flash attention, S^T formulation, 128-KEY tiles, double-buffered glds
// staging (64 KB LDS). 512 threads = 8 waves, 4 q-groups (wq) x 2 key-halves
// (wk); each wave 32 q x 64 keys. EXACT R6 state (best attn measured, <44us).
// R7 lessons reverted: setprio hurt (lockstep 8-wave barriers = T5 null
// regime, m190); XCD remap cut FETCH 5x but time-neutral (loads already
// hidden under compute) -- both removed for clean state.
// P/O packing via __float22bfloat162_rn; exp via __expf (both hazard-safe).
// Cross-wk O/l reduction via LDS overlay at epilogue. Key-half fully above
// the wave's queries skips compute. Mask iff max key (kbase+63) > min query.
// ---------------------------------------------------------------------------
__global__ __launch_bounds__(512, 4) void attn_mfma(const u16* __restrict__ Qh,
                                                    const u16* __restrict__ Kh,
                                                    const u16* __restrict__ Vt_g,
                                                    u16* __restrict__ Aa) {
    __shared__ u16 Ks[2][128 * 64];   // [buf][key][d-chunks swizzled], 16 KB each
    __shared__ u16 Vs[2][64 * 128];   // [buf][d][key-chunks swizzled], 16 KB each

    const int tid = threadIdx.x;
    const int w = tid >> 6;          // 0..7
    const int wq = w & 3;            // q-group: 32 queries
    const int wk = w >> 2;           // key-half: 64 keys of each 128-key tile
    const int lane = tid & 63;
    const int ln = lane & 15;
    const int quad = lane >> 4;

    // balanced task decode: blocks 0..255 heavy (qt 15..8), 256..511 light (0..7)
    const int i = blockIdx.x;
    const int half = i >> 8;
    const int r_ = i & 255;
    const int bh = r_ >> 3;
    const int j = r_ & 7;
    const int qt = half ? j : (15 - j);
    const int q0 = qt * 128;
    const int qw = q0 + wq * 32;

    const size_t base = (size_t)bh * T_SEQ * HEAD;
    const u16* Qb = Qh + base;
    const u16* Kb = Kh + base;
    const u16* Vtb = Vt_g + base;   // [d][T] rows

    // staging lane geometry (all 8 waves stage; each wave 2 K + 2 V chunks)
    const int l8 = lane >> 3;               // K sub-row 0..7
    const int gk = (lane & 7) ^ l8;         // K chunk fetched (8-slot XOR)
    const int l16 = lane >> 4;              // V sub-row 0..3
    const int c16 = lane & 15;              // V slot 0..15
    const int sls = __builtin_amdgcn_readfirstlane(w * 1024);

    // Q fragments (B-operand: lane holds col q=ln, k=quad*8+j), pre-scaled by 1/8
    frag8 qf[2][2];
#pragma unroll
    for (int qq = 0; qq < 2; ++qq)
#pragma unroll
        for (int kc = 0; kc < 2; ++kc)
            qf[qq][kc] = *(const frag8*)(Qb + (size_t)(qw + qq * 16 + ln) * HEAD +
                                         kc * 32 + quad * 8);

    const f32x4 zf = {0.f, 0.f, 0.f, 0.f};
    f32x4 o[4][2];            // O^T partial (this wave's key-half): [d-tile][q-tile]
    float rsl[2] = {0.f, 0.f};
#pragma unroll
    for (int dt = 0; dt < 4; ++dt)
#pragma unroll
        for (int qq = 0; qq < 2; ++qq) o[dt][qq] = zf;

    const int ktiles = qt + 1;   // 128-key tiles

    // ---- preload tile 0 into buf 0 ----
#pragma unroll
    for (int it = 0; it < 2; ++it) {
        const int krow = w * 16 + it * 8 + l8;
        gl2lds16(Kb + (size_t)krow * HEAD + gk * 8, &Ks[0][0] + sls + it * 512);
        const int vrow = w * 8 + it * 4 + l16;
        const int gv = c16 ^ (vrow & 7);
        gl2lds16(Vtb + (size_t)vrow * T_SEQ + gv * 8, &Vs[0][0] + sls + it * 512);
    }

    const int sw = ln & 7;
    const int hsel = quad >> 1;
    const int s_lo = ((quad & 1) * 2) * 16 + ln;   // src lane for dwords 0,1
    const int s_hi = s_lo + 16;                    // src lane for dwords 2,3

    for (int kt = 0; kt < ktiles; ++kt) {
        const int k0 = kt << 7;
        const int buf = kt & 1;
        __syncthreads();   // drains tile-kt glds (flew under previous compute)

        if (kt + 1 < ktiles) {
            const int k1 = k0 + 128;
#pragma unroll
            for (int it = 0; it < 2; ++it) {
                const int krow = w * 16 + it * 8 + l8;
                gl2lds16(Kb + (size_t)(k1 + krow) * HEAD + gk * 8,
                         &Ks[buf ^ 1][0] + sls + it * 512);
                const int vrow = w * 8 + it * 4 + l16;
                const int gv = c16 ^ (vrow & 7);
                gl2lds16(Vtb + (size_t)vrow * T_SEQ + k1 + gv * 8,
                         &Vs[buf ^ 1][0] + sls + it * 512);
            }
        }

        const int kbase = k0 + wk * 64;    // this wave's first key
        if (kbase <= qw + 31) {            // else: whole key-half masked -> skip
            // ---- S^T = K.Q^T per kk-tile, immediate exp+pack (bounded liveness)
            const bool msk = (kbase + 63 > qw);
            u32 pk[4][2][2];
#pragma unroll
            for (int kk = 0; kk < 4; ++kk) {
                f32x4 st[2] = {zf, zf};
#pragma unroll
                for (int kc = 0; kc < 2; ++kc) {
                    const int slot = ((kc * 4 + quad) ^ sw) * 8;
                    const frag8 kf = *(const frag8*)(&Ks[buf][0] +
                                                     (wk * 64 + kk * 16 + ln) * 64 + slot);
                    st[0] = __builtin_amdgcn_mfma_f32_16x16x32_bf16(kf, qf[0][kc], st[0], 0, 0, 0);
                    st[1] = __builtin_amdgcn_mfma_f32_16x16x32_bf16(kf, qf[1][kc], st[1], 0, 0, 0);
                }
#pragma unroll
                for (int qq = 0; qq < 2; ++qq) {
                    float e[4];
#pragma unroll
                    for (int reg = 0; reg < 4; ++reg) {
                        const int key = kbase + kk * 16 + quad * 4 + reg;
                        const int qg = qw + qq * 16 + ln;
                        float ev = __expf(st[qq][reg]);
                        if (msk) ev = (key <= qg) ? ev : 0.f;
                        e[reg] = ev;
                        rsl[qq] += ev;
                    }
                    pk[kk][qq][0] = pack_bf16x2(e[0], e[1]);
                    pk[kk][qq][1] = pack_bf16x2(e[2], e[3]);
                }
            }

            // ---- O^T += V^T . P^T  (B-frags built by quad-permute shuffles) ----
#pragma unroll
            for (int kc = 0; kc < 2; ++kc) {
                union { frag8 f; u32 d[4]; } pb[2];
#pragma unroll
                for (int qq = 0; qq < 2; ++qq) {
                    const u32 a00 = __shfl(pk[kc * 2][qq][0], s_lo, 64);
                    const u32 a01 = __shfl(pk[kc * 2][qq][1], s_lo, 64);
                    const u32 a02 = __shfl(pk[kc * 2][qq][0], s_hi, 64);
                    const u32 a03 = __shfl(pk[kc * 2][qq][1], s_hi, 64);
                    const u32 a10 = __shfl(pk[kc * 2 + 1][qq][0], s_lo, 64);
                    const u32 a11 = __shfl(pk[kc * 2 + 1][qq][1], s_lo, 64);
                    const u32 a12 = __shfl(pk[kc * 2 + 1][qq][0], s_hi, 64);
                    const u32 a13 = __shfl(pk[kc * 2 + 1][qq][1], s_hi, 64);
                    pb[qq].d[0] = hsel ? a10 : a00;
                    pb[qq].d[1] = hsel ? a11 : a01;
                    pb[qq].d[2] = hsel ? a12 : a02;
                    pb[qq].d[3] = hsel ? a13 : a03;
                }
                const int slotv = (((wk * 2 + kc) * 4 + quad) ^ sw) * 8;
#pragma unroll
                for (int dt = 0; dt < 4; ++dt) {
                    const frag8 vf = *(const frag8*)(&Vs[buf][0] + (dt * 16 + ln) * 128 + slotv);
                    o[dt][0] = __builtin_amdgcn_mfma_f32_16x16x32_bf16(vf, pb[0].f, o[dt][0], 0, 0, 0);
                    o[dt][1] = __builtin_amdgcn_mfma_f32_16x16x32_bf16(vf, pb[1].f, o[dt][1], 0, 0, 0);
                }
            }
        }
    }

    // ---- epilogue: quad-reduce l, cross-wk combine via LDS, normalize, write
#pragma unroll
    for (int qq = 0; qq < 2; ++qq) {
        rsl[qq] += __shfl_xor(rsl[qq], 16, 64);
        rsl[qq] += __shfl_xor(rsl[qq], 32, 64);
    }

    __syncthreads();   // all LDS compute reads done; overlay reduction buffers
    float* ored = (float*)&Ks[0][0];   // 32 KB: SoA [32 regs][256 lanes], conflict-free
    float* lred = (float*)&Vs[0][0];   // [2][256]
    if (wk == 1) {
#pragma unroll
        for (int dt = 0; dt < 4; ++dt)
#pragma unroll
            for (int qq = 0; qq < 2; ++qq)
#pragma unroll
                for (int rg = 0; rg < 4; ++rg)
                    ored[(dt * 8 + qq * 4 + rg) * 256 + wq * 64 + lane] = o[dt][qq][rg];
        lred[wq * 64 + lane] = rsl[0];
        lred[256 + wq * 64 + lane] = rsl[1];
    }
    __syncthreads();
    if (wk == 0) {
#pragma unroll
        for (int dt = 0; dt < 4; ++dt)
#pragma unroll
            for (int qq = 0; qq < 2; ++qq)
#pragma unroll
                for (int rg = 0; rg < 4; ++rg)
                    o[dt][qq][rg] += ored[(dt * 8 + qq * 4 + rg) * 256 + wq * 64 + lane];
        rsl[0] += lred[wq * 64 + lane];
        rsl[1] += lred[256 + wq * 64 + lane];

        const float inv0 = 1.f / rsl[0];
        const float inv1 = 1.f / rsl[1];
        const int b_ = bh >> 4, h_ = bh & (N_HEAD - 1);
#pragma unroll
        for (int qq = 0; qq < 2; ++qq) {
            const float inv = qq ? inv1 : inv0;
            const int qg = qw + qq * 16 + ln;
            u16* rowp = Aa + ((size_t)(b_ * T_SEQ + qg)) * E_DIM + h_ * HEAD;
#pragma unroll
            for (int dt = 0; dt < 4; ++dt)
#pragma unroll
                for (int rp = 0; rp < 2; ++rp) {
                    const u32 v = pack_bf16x2(o[dt][qq][2 * rp] * inv,
                                              o[dt][qq][2 * rp + 1] * inv);
                    *(u32*)(rowp + dt * 16 + quad * 4 + rp * 2) = v;
                }
        }
    }
}

// ---------------------------------------------------------------------------
extern "C" void kernel_launch(void* const* d_in, const int* in_sizes, int n_in,
                              void* d_out, int out_size, void* d_ws, size_t ws_size,
                              hipStream_t stream) {
    const float* q  = (const float*)d_in[0];
    const float* k  = (const float*)d_in[1];
    const float* v  = (const float*)d_in[2];
    const float* Wq = (const float*)d_in[3];
    const float* Wk = (const float*)d_in[4];
    const float* Wv = (const float*)d_in[5];
    const float* Wo = (const float*)d_in[6];

    u16* ws = (u16*)d_ws;
    const size_t M4 = (size_t)4 * 1024 * 1024;
    const size_t M1 = (size_t)1024 * 1024;
    u16* Wqb = ws + 3 * M4;
    u16* Wkb = ws + 3 * M4 + M1;
    u16* Wvb = ws + 3 * M4 + 2 * M1;
    u16* Wob = ws + 3 * M4 + 3 * M1;
    u16* Qh  = ws + 4 * M4;
    u16* Kh  = ws + 5 * M4;
    u16* Vht = ws + 6 * M4;   // [B,H,64,T]
    u16* Aa  = ws + 7 * M4;

    CastArgs ca;
    ca.src[0] = Wq; ca.src[1] = Wk; ca.src[2] = Wv; ca.src[3] = Wo;
    ca.dst[0] = Wqb; ca.dst[1] = Wkb; ca.dst[2] = Wvb; ca.dst[3] = Wob;
    ca.n[0] = ca.n[1] = ca.n[2] = ca.n[3] = (int)M1;
    ca.scale[0] = 0.125f;  // fold 1/sqrt(Dh) into Wq (exact in bf16)
    ca.scale[1] = ca.scale[2] = ca.scale[3] = 1.f;
    cast_f32_bf16<<<dim3(512, 4), 256, 0, stream>>>(ca);

    QkvArgs ga;
    ga.X[0] = q;   ga.X[1] = k;   ga.X[2] = v;      // f32 originals (fused cast)
    ga.W[0] = Wqb; ga.W[1] = Wkb; ga.W[2] = Wvb;
    ga.Y[0] = Qh;  ga.Y[1] = Kh;  ga.Y[2] = Vht;
    gemm_qkv<<<dim3(64, 8, 3), 256, 0, stream>>>(ga);

    attn_mfma<<<dim3(512), 512, 0, stream>>>(Qh, Kh, Vht, Aa);

    gemm_out<<<dim3(64, 8), 256, 0, stream>>>(Aa, Wob, (float*)d_out);
}

// Round 9
// 202.859 us; speedup vs baseline: 1.0232x; 1.0232x over previous
//
#include <hip/hip_runtime.h>
#include <hip/hip_bf16.h>
#include <cstddef>
#include <cstdint>

#define B_SZ   2
#define T_SEQ  2048
#define E_DIM  1024
#define N_HEAD 16
#define HEAD   64

typedef unsigned short u16;
typedef unsigned int u32;
using frag8 = __attribute__((ext_vector_type(8))) short;   // 8 bf16 = 4 VGPRs
using f32x4 = __attribute__((ext_vector_type(4))) float;   // MFMA accumulator

__device__ inline u16 f2bf(float x) {
    __hip_bfloat16 h = __float2bfloat16(x);
    return *reinterpret_cast<u16*>(&h);
}

// pair-pack two f32 -> one u32 of 2x bf16 (lo=first, hi=second), RNE.
// COMPILER-emitted conversion (hazard-safe) -- round-5 lesson: raw inline-asm
// around transcendental/convert ops corrupted results.
__device__ inline u32 pack_bf16x2(float lo, float hi) {
    float2 t; t.x = lo; t.y = hi;
    __hip_bfloat162 p = __float22bfloat162_rn(t);
    return *reinterpret_cast<u32*>(&p);
}

// async global->LDS, 16 B per lane. LDS dest is wave-uniform base; HW adds lane*16B.
__device__ inline void gl2lds16(const void* g, void* l) {
    auto gp = reinterpret_cast<const __attribute__((address_space(1))) unsigned int*>(
        reinterpret_cast<uintptr_t>(g));
    auto lp = reinterpret_cast<__attribute__((address_space(3))) unsigned int*>(
        reinterpret_cast<uintptr_t>(l));
    __builtin_amdgcn_global_load_lds(gp, lp, 16, 0, 0);
}

// ---------------------------------------------------------------------------
// Cast 7 fp32 tensors to bf16 (with per-tensor scale) in one dispatch.
// R8 lesson: fusing q/k/v cast into the GEMM A-path regressed 27 us (VGPR
// round-trip exposes vmcnt wait every K-step; T14 needs a long compute phase).
// Standalone cast + global_load_lds GEMM staging is the verified optimum.
// Wq is pre-scaled by 1/8 (EXACT in bf16) so attention scores need no scaling.
// ---------------------------------------------------------------------------
struct CastArgs {
    const float* src[7];
    u16* dst[7];
    int n[7];
    float scale[7];
};

__global__ __launch_bounds__(256) void cast_f32_bf16(CastArgs a) {
    const int t = blockIdx.y;
    const int i0 = (blockIdx.x * 256 + threadIdx.x) * 8;
    if (i0 >= a.n[t]) return;
    const float sc = a.scale[t];
    const float4 f0 = *(const float4*)(a.src[t] + i0);
    const float4 f1 = *(const float4*)(a.src[t] + i0 + 4);
    uint4 r;
    r.x = pack_bf16x2(f0.x * sc, f0.y * sc);
    r.y = pack_bf16x2(f0.z * sc, f0.w * sc);
    r.z = pack_bf16x2(f1.x * sc, f1.y * sc);
    r.w = pack_bf16x2(f1.z * sc, f1.w * sc);
    *(uint4*)(a.dst[t] + i0) = r;
}

// ---------------------------------------------------------------------------
// bf16 MFMA GEMM core: Y = X @ W^T. BM=64 x BN=128, BK=64 -- the empirical
// optimum across 5 rounds of structure search (drain 44.0 us beats 128^2
// drain 50.1, 256^2 ring 54.7, 128^2 32-col ring 47.9, fused-cast 70.9).
// DOUBLE-BUFFERED width-16 glds staging (48 KB -> 3 blocks/CU). 4 waves,
// each 32x64. 8-slot XOR chunk swizzle (0 conflicts measured).
// mode 0: bf16 scatter [B,H,T,64]; mode 1: fp32 [M,1024]; mode 2: bf16 [B,H,64,T]
// ---------------------------------------------------------------------------
__device__ inline void gemm_core(const u16* __restrict__ X,
                                 const u16* __restrict__ W,
                                 void* __restrict__ Yv, int mode,
                                 int bm0, int bn0) {
    __shared__ u16 As[2][64 * 64];    // 8 KB x2
    __shared__ u16 Bs[2][128 * 64];   // 16 KB x2

    const int tid = threadIdx.x;
    const int w = tid >> 6;
    const int lane = tid & 63;
    const int ln = lane & 15;
    const int quad = lane >> 4;
    const int wm = (w & 1) * 32;
    const int wn = (w >> 1) * 64;

    const int l8 = lane >> 3;              // sub-row 0..7
    const int g = (lane & 7) ^ l8;         // global chunk fetched (XOR swizzle)

    const u16* Ag = X + (size_t)(bm0 + w * 16 + l8) * 1024 + g * 8;
    const u16* Bg = W + (size_t)(bn0 + w * 32 + l8) * 1024 + g * 8;
    const int al = __builtin_amdgcn_readfirstlane(w * 1024);
    const int bl = __builtin_amdgcn_readfirstlane(w * 2048);

    const f32x4 zf = {0.f, 0.f, 0.f, 0.f};
    f32x4 acc[2][4];
#pragma unroll
    for (int mi = 0; mi < 2; ++mi)
#pragma unroll
        for (int nj = 0; nj < 4; ++nj) acc[mi][nj] = zf;

    const int sw = ln & 7;

    // preload K-tile 0 into buffer 0
    gl2lds16(Ag, &As[0][0] + al);
    gl2lds16(Ag + 8 * 1024, &As[0][0] + al + 512);
#pragma unroll
    for (int it = 0; it < 4; ++it)
        gl2lds16(Bg + (size_t)it * 8 * 1024, &Bs[0][0] + bl + it * 512);

    for (int k0 = 0; k0 < 1024; k0 += 64) {
        const int buf = (k0 >> 6) & 1;
        __syncthreads();   // drains this tile's glds; prev tile's reads done

        if (k0 + 64 < 1024) {
            gl2lds16(Ag + k0 + 64, &As[buf ^ 1][0] + al);
            gl2lds16(Ag + 8 * 1024 + k0 + 64, &As[buf ^ 1][0] + al + 512);
#pragma unroll
            for (int it = 0; it < 4; ++it)
                gl2lds16(Bg + (size_t)it * 8 * 1024 + k0 + 64,
                         &Bs[buf ^ 1][0] + bl + it * 512);
        }

        frag8 a[2][2], b[4][2];
#pragma unroll
        for (int kc = 0; kc < 2; ++kc) {
            const int slot = ((kc * 4 + quad) ^ sw) * 8;
#pragma unroll
            for (int mi = 0; mi < 2; ++mi)
                a[mi][kc] = *(const frag8*)(&As[buf][0] + (wm + mi * 16 + ln) * 64 + slot);
#pragma unroll
            for (int nj = 0; nj < 4; ++nj)
                b[nj][kc] = *(const frag8*)(&Bs[buf][0] + (wn + nj * 16 + ln) * 64 + slot);
        }
#pragma unroll
        for (int kc = 0; kc < 2; ++kc)
#pragma unroll
            for (int mi = 0; mi < 2; ++mi)
#pragma unroll
                for (int nj = 0; nj < 4; ++nj)
                    acc[mi][nj] = __builtin_amdgcn_mfma_f32_16x16x32_bf16(
                        a[mi][kc], b[nj][kc], acc[mi][nj], 0, 0, 0);
    }

    // C/D layout: col = lane&15, row = quad*4 + reg
#pragma unroll
    for (int mi = 0; mi < 2; ++mi)
#pragma unroll
        for (int nj = 0; nj < 4; ++nj)
#pragma unroll
            for (int reg = 0; reg < 4; ++reg) {
                const int m = bm0 + wm + mi * 16 + quad * 4 + reg;
                const int n = bn0 + wn + nj * 16 + ln;
                if (mode == 1) {
                    ((float*)Yv)[(size_t)m * E_DIM + n] = acc[mi][nj][reg];
                } else {
                    const int b_ = m >> 11, t_ = m & (T_SEQ - 1);
                    const int h_ = n >> 6, d_ = n & (HEAD - 1);
                    const size_t idx = (mode == 0)
                        ? (((size_t)(b_ * N_HEAD + h_)) * T_SEQ + t_) * HEAD + d_
                        : (((size_t)(b_ * N_HEAD + h_)) * HEAD + d_) * T_SEQ + t_;
                    ((u16*)Yv)[idx] = f2bf(acc[mi][nj][reg]);
                }
            }
}

struct QkvArgs {
    const u16* X[3];
    const u16* W[3];
    u16* Y[3];
};

__global__ __launch_bounds__(256, 3) void gemm_qkv(QkvArgs a) {
    const int z = blockIdx.z;
    gemm_core(a.X[z], a.W[z], a.Y[z], z == 2 ? 2 : 0,
              blockIdx.x * 64, blockIdx.y * 128);
}

__global__ __launch_bounds__(256, 3) void gemm_out(const u16* __restrict__ X,
                                                   const u16* __restrict__ W,
                                                   float* __restrict__ Y) {
    gemm_core(X, W, Y, 1, blockIdx.x * 64, blockIdx.y * 128);
}

// ---------------------------------------------------------------------------
// Flash attention, S^T formulation. ROUND-17: occupancy was GRID-bound, not
// LDS-bound (512 blocks x 8 waves = 16 waves/CU max; measured 26%). Now
// 1024 blocks x 512 threads: q-tiles of 64 queries, 8 waves = 4 q-groups
// (wq, 16 q each) x 2 key-halves (wk, 32 keys of each 64-KEY tile). KVBLK=64
// double-buffered LDS = 32 KB -> 4 blocks/CU = 32 waves/CU (100% cap).
// Strict specialization of the R1-verified geometry: the qq dimension is
// deleted, all swizzle/shuffle/PV index math carries over with sizes halved
// (K/V swizzle keys both = ln&7; PV B-frag still K=32 over the wave's 2
// kk-groups). Finer 32-key/16-q granularity sharpens causal skip.
// Cross-wk O/l reduction fits ONE 16 KB LDS pass now. No setprio (T5 null in
// lockstep blocks, R7). No XCD remap (time-neutral, R7).
// ---------------------------------------------------------------------------
__global__ __launch_bounds__(512, 8) void attn_mfma(const u16* __restrict__ Qh,
                                                    const u16* __restrict__ Kh,
                                                    const u16* __restrict__ Vt_g,
                                                    u16* __restrict__ Aa) {
    __shared__ u16 Ks[2][64 * 64];   // [buf][key][d-chunks swizzled], 8 KB each
    __shared__ u16 Vs[2][64 * 64];   // [buf][d][key-chunks swizzled], 8 KB each

    const int tid = threadIdx.x;
    const int w = tid >> 6;          // 0..7
    const int wq = w & 3;            // q-group: 16 queries
    const int wk = w >> 2;           // key-half: 32 keys of each 64-key tile
    const int lane = tid & 63;
    const int ln = lane & 15;
    const int quad = lane >> 4;

    // balanced task decode: blocks 0..511 heavy (qt 31..16), 512..1023 light
    // (qt 0..15). CU holds ~2 heavy + 2 light -> per-CU tile work ~constant.
    const int i = blockIdx.x;
    const int half = i >> 9;
    const int r_ = i & 511;
    const int bh = r_ >> 4;
    const int j = r_ & 15;
    const int qt = half ? j : (31 - j);
    const int q0 = qt * 64;
    const int qw = q0 + wq * 16;

    const size_t base = (size_t)bh * T_SEQ * HEAD;
    const u16* Qb = Qh + base;
    const u16* Kb = Kh + base;
    const u16* Vtb = Vt_g + base;   // [d][T] rows

    // staging lane geometry: per wave 1 K glds (8 key-rows x 64 d) and
    // 1 V glds (8 d-rows x 64 keys); both use chunk XOR key = row&7 = l8.
    const int l8 = lane >> 3;               // sub-row 0..7
    const int gk = (lane & 7) ^ l8;         // chunk fetched (8-slot XOR)
    const int sls = __builtin_amdgcn_readfirstlane(w * 512);

    // Q fragments (B-operand: lane holds col q=ln, k=quad*8+j), pre-scaled by 1/8
    frag8 qf[2];
#pragma unroll
    for (int kc = 0; kc < 2; ++kc)
        qf[kc] = *(const frag8*)(Qb + (size_t)(qw + ln) * HEAD + kc * 32 + quad * 8);

    const f32x4 zf = {0.f, 0.f, 0.f, 0.f};
    f32x4 o[4];               // O^T partial (this wave's key-half): [d-tile]
    float rsl = 0.f;
#pragma unroll
    for (int dt = 0; dt < 4; ++dt) o[dt] = zf;

    const int ktiles = qt + 1;   // 64-key tiles (keys 0..q0+63)

    // ---- preload tile 0 into buf 0 ----
    {
        const int row = w * 8 + l8;
        gl2lds16(Kb + (size_t)row * HEAD + gk * 8, &Ks[0][0] + sls);
        gl2lds16(Vtb + (size_t)row * T_SEQ + gk * 8, &Vs[0][0] + sls);
    }

    const int sw = ln & 7;
    const int hsel = quad >> 1;
    const int s_lo = ((quad & 1) * 2) * 16 + ln;   // src lane for dwords 0,1
    const int s_hi = s_lo + 16;                    // src lane for dwords 2,3

    for (int kt = 0; kt < ktiles; ++kt) {
        const int k0 = kt << 6;
        const int buf = kt & 1;
        __syncthreads();   // drains tile-kt glds (flew under previous compute)

        if (kt + 1 < ktiles) {
            const int k1 = k0 + 64;
            const int row = w * 8 + l8;
            gl2lds16(Kb + (size_t)(k1 + row) * HEAD + gk * 8, &Ks[buf ^ 1][0] + sls);
            gl2lds16(Vtb + (size_t)row * T_SEQ + k1 + gk * 8, &Vs[buf ^ 1][0] + sls);
        }

        const int kbase = k0 + wk * 32;    // this wave's first key
        if (kbase <= qw + 15) {            // else: whole key-half masked -> skip
            // ---- S^T = K.Q^T per kk-subtile, immediate exp+pack ----
            const bool msk = (kbase + 31 > qw);
            u32 pk[2][2];
#pragma unroll
            for (int kk = 0; kk < 2; ++kk) {
                f32x4 st = zf;
#pragma unroll
                for (int kc = 0; kc < 2; ++kc) {
                    const int slot = ((kc * 4 + quad) ^ sw) * 8;
                    const frag8 kf = *(const frag8*)(&Ks[buf][0] +
                                                     (wk * 32 + kk * 16 + ln) * 64 + slot);
                    st = __builtin_amdgcn_mfma_f32_16x16x32_bf16(kf, qf[kc], st, 0, 0, 0);
                }
                float e[4];
#pragma unroll
                for (int reg = 0; reg < 4; ++reg) {
                    const int key = kbase + kk * 16 + quad * 4 + reg;
                    const int qg = qw + ln;
                    float ev = __expf(st[reg]);
                    if (msk) ev = (key <= qg) ? ev : 0.f;
                    e[reg] = ev;
                    rsl += ev;
                }
                pk[kk][0] = pack_bf16x2(e[0], e[1]);
                pk[kk][1] = pack_bf16x2(e[2], e[3]);
            }

            // ---- O^T += V^T . P^T  (B-frag built by quad-permute shuffles) ----
            union { frag8 f; u32 d[4]; } pb;
            {
                const u32 a00 = __shfl(pk[0][0], s_lo, 64);
                const u32 a01 = __shfl(pk[0][1], s_lo, 64);
                const u32 a02 = __shfl(pk[0][0], s_hi, 64);
                const u32 a03 = __shfl(pk[0][1], s_hi, 64);
                const u32 a10 = __shfl(pk[1][0], s_lo, 64);
                const u32 a11 = __shfl(pk[1][1], s_lo, 64);
                const u32 a12 = __shfl(pk[1][0], s_hi, 64);
                const u32 a13 = __shfl(pk[1][1], s_hi, 64);
                pb.d[0] = hsel ? a10 : a00;
                pb.d[1] = hsel ? a11 : a01;
                pb.d[2] = hsel ? a12 : a02;
                pb.d[3] = hsel ? a13 : a03;
            }
            const int slotv = ((wk * 4 + quad) ^ sw) * 8;
#pragma unroll
            for (int dt = 0; dt < 4; ++dt) {
                const frag8 vf = *(const frag8*)(&Vs[buf][0] + (dt * 16 + ln) * 64 + slotv);
                o[dt] = __builtin_amdgcn_mfma_f32_16x16x32_bf16(vf, pb.f, o[dt], 0, 0, 0);
            }
        }
    }

    // ---- epilogue: quad-reduce l, cross-wk combine via LDS, normalize, write
    rsl += __shfl_xor(rsl, 16, 64);
    rsl += __shfl_xor(rsl, 32, 64);

    __syncthreads();   // all LDS compute reads done; overlay reduction buffers
    float* ored = (float*)&Ks[0][0];   // 16 KB: SoA [16 regs][256 lanes]
    float* lred = (float*)&Vs[0][0];   // [256]
    if (wk == 1) {
#pragma unroll
        for (int dt = 0; dt < 4; ++dt)
#pragma unroll
            for (int rg = 0; rg < 4; ++rg)
                ored[(dt * 4 + rg) * 256 + wq * 64 + lane] = o[dt][rg];
        lred[wq * 64 + lane] = rsl;
    }
    __syncthreads();
    if (wk == 0) {
#pragma unroll
        for (int dt = 0; dt < 4; ++dt)
#pragma unroll
            for (int rg = 0; rg < 4; ++rg)
                o[dt][rg] += ored[(dt * 4 + rg) * 256 + wq * 64 + lane];
        rsl += lred[wq * 64 + lane];

        const float inv = 1.f / rsl;
        const int b_ = bh >> 4, h_ = bh & (N_HEAD - 1);
        const int qg = qw + ln;
        u16* rowp = Aa + ((size_t)(b_ * T_SEQ + qg)) * E_DIM + h_ * HEAD;
#pragma unroll
        for (int dt = 0; dt < 4; ++dt)
#pragma unroll
            for (int rp = 0; rp < 2; ++rp) {
                const u32 v = pack_bf16x2(o[dt][2 * rp] * inv,
                                          o[dt][2 * rp + 1] * inv);
                *(u32*)(rowp + dt * 16 + quad * 4 + rp * 2) = v;
            }
    }
}

// ---------------------------------------------------------------------------
extern "C" void kernel_launch(void* const* d_in, const int* in_sizes, int n_in,
                              void* d_out, int out_size, void* d_ws, size_t ws_size,
                              hipStream_t stream) {
    const float* q  = (const float*)d_in[0];
    const float* k  = (const float*)d_in[1];
    const float* v  = (const float*)d_in[2];
    const float* Wq = (const float*)d_in[3];
    const float* Wk = (const float*)d_in[4];
    const float* Wv = (const float*)d_in[5];
    const float* Wo = (const float*)d_in[6];

    u16* ws = (u16*)d_ws;
    const size_t M4 = (size_t)4 * 1024 * 1024;
    const size_t M1 = (size_t)1024 * 1024;
    u16* qb  = ws;
    u16* kb  = ws + M4;
    u16* vb  = ws + 2 * M4;
    u16* Wqb = ws + 3 * M4;
    u16* Wkb = ws + 3 * M4 + M1;
    u16* Wvb = ws + 3 * M4 + 2 * M1;
    u16* Wob = ws + 3 * M4 + 3 * M1;
    u16* Qh  = ws + 4 * M4;
    u16* Kh  = ws + 5 * M4;
    u16* Vht = ws + 6 * M4;   // [B,H,64,T]
    u16* Aa  = ws + 7 * M4;

    CastArgs ca;
    ca.src[0] = q;  ca.src[1] = k;  ca.src[2] = v;
    ca.src[3] = Wq; ca.src[4] = Wk; ca.src[5] = Wv; ca.src[6] = Wo;
    ca.dst[0] = qb;  ca.dst[1] = kb;  ca.dst[2] = vb;
    ca.dst[3] = Wqb; ca.dst[4] = Wkb; ca.dst[5] = Wvb; ca.dst[6] = Wob;
    ca.n[0] = ca.n[1] = ca.n[2] = (int)M4;
    ca.n[3] = ca.n[4] = ca.n[5] = ca.n[6] = (int)M1;
    ca.scale[0] = ca.scale[1] = ca.scale[2] = 1.f;
    ca.scale[3] = 0.125f;  // fold 1/sqrt(Dh) into Wq (exact in bf16)
    ca.scale[4] = ca.scale[5] = ca.scale[6] = 1.f;
    cast_f32_bf16<<<dim3(2048, 7), 256, 0, stream>>>(ca);

    QkvArgs ga;
    ga.X[0] = qb;  ga.X[1] = kb;  ga.X[2] = vb;
    ga.W[0] = Wqb; ga.W[1] = Wkb; ga.W[2] = Wvb;
    ga.Y[0] = Qh;  ga.Y[1] = Kh;  ga.Y[2] = Vht;
    gemm_qkv<<<dim3(64, 8, 3), 256, 0, stream>>>(ga);

    attn_mfma<<<dim3(1024), 512, 0, stream>>>(Qh, Kh, Vht, Aa);

    gemm_out<<<dim3(64, 8), 256, 0, stream>>>(Aa, Wob, (float*)d_out);
}